// Round 1
// baseline (460.816 us; speedup 1.0000x reference)
//
#include <hip/hip_runtime.h>
#include <math.h>

#define NROWS 65536
#define DIM   512
#define NCLS  64

// ws layout (4-byte words):
//   0        lossAcc (f32)
//   1        accAcc  (f32)
//   2..66    p2[64]  (f32)
//   66..130  counts[64]  (i32)
//   130..194 cursors[64] (i32)
//   194..258 offsets[64] (i32)
//   260..65796            perm[65536] (i32)
//   65796..98564          protoT[512*64] (f32), protoT[d*64+c]
#define WS_P2      2
#define WS_COUNTS  66
#define WS_CURSORS 130
#define WS_OFFSETS 194
#define WS_PERM    260
#define WS_PROTOT  (260 + 65536)

// ---------------- histogram ----------------
__global__ __launch_bounds__(256) void k_hist(const int* __restrict__ labels,
                                              int* __restrict__ counts) {
    __shared__ int h[NCLS];
    int t = threadIdx.x;
    if (t < NCLS) h[t] = 0;
    __syncthreads();
    int i = blockIdx.x * 256 + t;
    atomicAdd(&h[labels[i]], 1);
    __syncthreads();
    if (t < NCLS) atomicAdd(&counts[t], h[t]);
}

// ---------------- prefix sum (tiny) ----------------
__global__ void k_prefix(const int* __restrict__ counts,
                         int* __restrict__ offsets, int* __restrict__ cursors) {
    if (threadIdx.x == 0 && blockIdx.x == 0) {
        int run = 0;
        for (int c = 0; c < NCLS; ++c) {
            offsets[c] = run;
            cursors[c] = run;
            run += counts[c];
        }
    }
}

// ---------------- scatter row indices into class buckets ----------------
__global__ __launch_bounds__(256) void k_scatter(const int* __restrict__ labels,
                                                 int* __restrict__ cursors,
                                                 int* __restrict__ perm) {
    int i = blockIdx.x * 256 + threadIdx.x;
    int l = labels[i];
    int pos = atomicAdd(&cursors[l], 1);
    perm[pos] = i;
}

// ---------------- per-class mean prototypes (gathered, coalesced) ----------
// grid = 64 classes * 4 dim-chunks = 256 blocks; block = 512 threads
// thread = (row-group g in 0..3) x (dim lane in 0..127)
__global__ __launch_bounds__(512) void k_proto(const float* __restrict__ emb,
                                               const int* __restrict__ counts,
                                               const int* __restrict__ offsets,
                                               const int* __restrict__ perm,
                                               float* __restrict__ protoT,
                                               float* __restrict__ p2) {
    int c     = blockIdx.x >> 2;
    int chunk = blockIdx.x & 3;
    int dl    = threadIdx.x & 127;
    int g     = threadIdx.x >> 7;
    int d     = chunk * 128 + dl;
    int cnt   = counts[c];
    int base  = offsets[c];

    float acc = 0.f;
#pragma unroll 8
    for (int i = g; i < cnt; i += 4) {
        int r = perm[base + i];                     // wave-uniform -> s_load
        acc += emb[(size_t)r * DIM + d];            // coalesced 512B segments
    }

    __shared__ float red[512];
    red[threadIdx.x] = acc;
    __syncthreads();
    if (g == 0) {   // waves 0,1 entirely (tid 0..127)
        float s = red[dl] + red[dl + 128] + red[dl + 256] + red[dl + 384];
        float mean = (cnt > 0) ? s / (float)cnt : 0.f;
        protoT[d * NCLS + c] = mean;
        float sq = mean * mean;
#pragma unroll
        for (int off = 32; off > 0; off >>= 1) sq += __shfl_down(sq, off, 64);
        if ((threadIdx.x & 63) == 0) atomicAdd(&p2[c], sq);
    }
}

// ---------------- main: distances + log-softmax + argmax + reduce ----------
// grid = 256 blocks * 256 threads, 256 rows per block, one row per thread
#define TILE 256
#define DC   32
__global__ __launch_bounds__(256) void k_logits(const float* __restrict__ emb,
                                                const int* __restrict__ labels,
                                                const float* __restrict__ protoT,
                                                const float* __restrict__ p2,
                                                float* __restrict__ lossAcc,
                                                float* __restrict__ accAcc) {
    __shared__ float eT[TILE][DC + 1];   // pad -> conflict-free column reads
    int t  = threadIdx.x;
    int r0 = blockIdx.x * TILE;

    float acc[NCLS];
#pragma unroll
    for (int c = 0; c < NCLS; ++c) acc[c] = 0.f;
    float e2 = 0.f;

    const float4* gsrc = (const float4*)emb;  // DIM/4 = 128 float4 per row

    // prefetch chunk 0 into registers
    float4 buf[8];
#pragma unroll
    for (int k = 0; k < 8; ++k) {
        int f = k * 256 + t;
        int row = f >> 3, c4 = f & 7;
        buf[k] = gsrc[(size_t)(r0 + row) * (DIM / 4) + c4];
    }

    for (int ch = 0; ch < DIM / DC; ++ch) {
        __syncthreads();     // previous chunk's LDS reads complete
#pragma unroll
        for (int k = 0; k < 8; ++k) {
            int f = k * 256 + t;
            int row = f >> 3, c4 = f & 7;
            eT[row][c4 * 4 + 0] = buf[k].x;
            eT[row][c4 * 4 + 1] = buf[k].y;
            eT[row][c4 * 4 + 2] = buf[k].z;
            eT[row][c4 * 4 + 3] = buf[k].w;
        }
        __syncthreads();
        if (ch + 1 < DIM / DC) {   // prefetch next chunk while computing
            int b4 = (ch + 1) * (DC / 4);
#pragma unroll
            for (int k = 0; k < 8; ++k) {
                int f = k * 256 + t;
                int row = f >> 3, c4 = f & 7;
                buf[k] = gsrc[(size_t)(r0 + row) * (DIM / 4) + b4 + c4];
            }
        }
        int d0 = ch * DC;
#pragma unroll 4
        for (int dd = 0; dd < DC; ++dd) {
            float ev = eT[t][dd];
            e2 += ev * ev;
            const float* pr = &protoT[(d0 + dd) * NCLS];  // uniform -> s_load
#pragma unroll
            for (int c = 0; c < NCLS; ++c) acc[c] += ev * pr[c];
        }
    }

    // epilogue: logits, log-softmax, argmax
    int lab = labels[r0 + t];
    float m = -INFINITY;
    int bi = 0;
    float logit_lab = 0.f;
#pragma unroll
    for (int c = 0; c < NCLS; ++c) {
        float d2 = e2 + p2[c] - 2.f * acc[c];
        d2 = fmaxf(d2, 1e-12f);
        float lg = -sqrtf(d2);
        acc[c] = lg;
        if (lg > m) { m = lg; bi = c; }   // strict > keeps first max (jnp.argmax)
        if (c == lab) logit_lab = lg;
    }
    float se = 0.f;
#pragma unroll
    for (int c = 0; c < NCLS; ++c) se += __expf(acc[c] - m);
    float lse = __logf(se) + m;
    float nll = lse - logit_lab;
    float correct = (bi == lab) ? 1.f : 0.f;

    // wave reduce (64) then block reduce
#pragma unroll
    for (int off = 32; off > 0; off >>= 1) {
        nll     += __shfl_down(nll, off, 64);
        correct += __shfl_down(correct, off, 64);
    }
    __shared__ float rbuf[8];
    int wid = t >> 6, lane = t & 63;
    if (lane == 0) { rbuf[wid] = nll; rbuf[4 + wid] = correct; }
    __syncthreads();
    if (t == 0) {
        float a = rbuf[0] + rbuf[1] + rbuf[2] + rbuf[3];
        float b = rbuf[4] + rbuf[5] + rbuf[6] + rbuf[7];
        atomicAdd(lossAcc, a);
        atomicAdd(accAcc, b);
    }
}

// ---------------- finalize ----------------
__global__ void k_final(const float* __restrict__ lossAcc,
                        const float* __restrict__ accAcc,
                        float* __restrict__ out) {
    if (threadIdx.x == 0 && blockIdx.x == 0) {
        out[0] = lossAcc[0] * (1.f / NROWS);
        out[1] = accAcc[0] * (1.f / NROWS);
    }
}

extern "C" void kernel_launch(void* const* d_in, const int* in_sizes, int n_in,
                              void* d_out, int out_size, void* d_ws, size_t ws_size,
                              hipStream_t stream) {
    const float* emb    = (const float*)d_in[0];
    const int*   labels = (const int*)d_in[1];
    float* out = (float*)d_out;

    float* wsf = (float*)d_ws;
    int*   wsi = (int*)d_ws;
    float* lossAcc = wsf + 0;
    float* accAcc  = wsf + 1;
    float* p2      = wsf + WS_P2;
    int*   counts  = wsi + WS_COUNTS;
    int*   cursors = wsi + WS_CURSORS;
    int*   offsets = wsi + WS_OFFSETS;
    int*   perm    = wsi + WS_PERM;
    float* protoT  = wsf + WS_PROTOT;

    // zero accumulators / counts / cursors (ws is poisoned 0xAA each call)
    hipMemsetAsync(d_ws, 0, WS_PERM * sizeof(int), stream);

    k_hist<<<NROWS / 256, 256, 0, stream>>>(labels, counts);
    k_prefix<<<1, 64, 0, stream>>>(counts, offsets, cursors);
    k_scatter<<<NROWS / 256, 256, 0, stream>>>(labels, cursors, perm);
    k_proto<<<NCLS * 4, 512, 0, stream>>>(emb, counts, offsets, perm, protoT, p2);
    k_logits<<<NROWS / TILE, TILE, 0, stream>>>(emb, labels, protoT, p2,
                                                lossAcc, accAcc);
    k_final<<<1, 64, 0, stream>>>(lossAcc, accAcc, out);
}